// Round 5
// baseline (89.691 us; speedup 1.0000x reference)
//
#include <hip/hip_runtime.h>
#include <hip/hip_bf16.h>
#include <math.h>

#define KC 64
#define DD 128
#define NN 4096

// ws float offsets
#define OFF_MUHAT 0u       // 8192
#define OFF_KAP   8192u    // 64
#define OFF_LOGC  8256u    // 64
#define OFF_AA    8320u    // 64
#define OFF_SUMSP 8384u    // 256*128 = 32768  (per-block class-sum partials)
#define OFF_CNTP  41152u   // 256               (per-block count partials)
#define OFF_PP    41408u   // 256*64 = 16384    (per-block P-row partials)

#define LOG2PI 1.8378770664093453f
#define LN2    0.6931471805599453f
#define GAMMALN64 201.00931639928152f

__device__ __forceinline__ float wave_sum(float v) {
  #pragma unroll
  for (int off = 32; off > 0; off >>= 1) v += __shfl_xor(v, off, 64);
  return v;
}

// Kernel A: block b = (sub, c); sub = b>>6 owns rows [sub*1024, sub*1024+1024),
// c = b&63 owns class c. Finds its rows, normalizes them in-reg, computes
// L[n,:] via LDS dot, accumulates P-row-c / class-sum / count with NO atomics.
__global__ __launch_bounds__(512) void k_classes(const float* __restrict__ feat,
                                                 const float* __restrict__ musp,
                                                 const float* __restrict__ rho,
                                                 const int* __restrict__ lab,
                                                 float* __restrict__ ws) {
  __shared__ __align__(16) float mu_t[DD][65];   // mu_t[d][r] = muhat[r][d]
  __shared__ float kap_s[KC], logC_s[KC];
  __shared__ __align__(16) float f_s[8][132];
  __shared__ float redS[8][DD];
  __shared__ float redP[8][KC];
  __shared__ int wl[1024];
  __shared__ int wl_cnt;

  const int tid = threadIdx.x;
  const int w = tid >> 6, l = tid & 63;
  const int b = blockIdx.x, c = b & 63, sub = b >> 6;
  if (tid == 0) wl_cnt = 0;

  // stage normalized mus (transposed) — redundant per block, trivial
  #pragma unroll
  for (int rr = 0; rr < 8; ++rr) {
    int r = w * 8 + rr;
    float x0 = musp[r * DD + l];
    float x1 = musp[r * DD + 64 + l];
    float ss = wave_sum(x0 * x0 + x1 * x1);
    float inv = 1.f / fmaxf(sqrtf(ss), 1e-12f);
    mu_t[l][r]      = x0 * inv;
    mu_t[l + 64][r] = x1 * inv;
  }
  if (tid < KC) {
    float x = rho[tid];
    float sp = fmaxf(x, 0.f) + log1pf(expf(-fabsf(x)));
    float kp = fmaxf(sp, 1e-6f);
    kap_s[tid] = kp;
    float logI;
    if (kp < 1e-3f)
      logI = 63.f * logf(kp * 0.5f + 1e-12f) - GAMMALN64;
    else
      logI = kp - 0.5f * logf(6.283185307179586f * kp + 1e-12f);
    logC_s[tid] = -63.f * logf(kp + 1e-12f) - 64.f * LOG2PI - logI;
  }
  __syncthreads();

  // block 0 publishes muhat + per-class consts for k_final
  if (b == 0) {
    for (int idx = tid; idx < KC * DD; idx += 512)
      ws[OFF_MUHAT + idx] = mu_t[idx & 127][idx >> 7];
    if (tid < KC) {
      float kp = kap_s[tid];
      float kc = fmaxf(kp, 1e-8f);
      float Aav = (kc > 50.f) ? (1.f - 127.f / (2.f * kc)) : (kc * (1.f / 128.f));
      ws[OFF_KAP + tid]  = kp;
      ws[OFF_LOGC + tid] = logC_s[tid];
      ws[OFF_AA + tid]   = Aav;
    }
  }

  // worklist: rows in our window with label == c
  const int base = sub * 1024;
  for (int t = tid; t < 1024; t += 512) {
    if (lab[base + t] == c) {
      int p = atomicAdd(&wl_cnt, 1);   // LDS atomic, tiny
      wl[p] = base + t;
    }
  }
  __syncthreads();
  const int m = wl_cnt;

  float accP = 0.f, s0 = 0.f, s1 = 0.f;
  const float2* feat2 = (const float2*)feat;
  for (int e = w; e < m; e += 8) {
    int n = wl[e];
    float2 f2 = feat2[n * 64 + l];                 // lane l holds dims 2l, 2l+1
    float ss = wave_sum(f2.x * f2.x + f2.y * f2.y);
    float inv = 1.f / fmaxf(sqrtf(ss), 1e-12f);
    float x0 = f2.x * inv, x1 = f2.y * inv;
    s0 += x0; s1 += x1;
    *(float2*)&f_s[w][2 * l] = make_float2(x0, x1); // per-wave buffer
    __builtin_amdgcn_wave_barrier();                // pin order: write before reads
    float acc0 = 0.f, acc1 = 0.f;
    #pragma unroll
    for (int d = 0; d < DD; d += 4) {
      float4 fb = *(const float4*)&f_s[w][d];       // broadcast read
      acc0 += fb.x * mu_t[d][l]     + fb.z * mu_t[d + 2][l];
      acc1 += fb.y * mu_t[d + 1][l] + fb.w * mu_t[d + 3][l];
    }
    float Lj = logC_s[l] + kap_s[l] * (acc0 + acc1);
    float a = __shfl(Lj, c, 64);                    // L[n, c]
    float mm = fmaxf(a, Lj);
    accP += a + LN2 - (mm + log1pf(expf(-fabsf(a - Lj))));
  }

  // cross-wave reduce, plain stores (no global atomics)
  redP[w][l] = accP;
  redS[w][2 * l] = s0;
  redS[w][2 * l + 1] = s1;
  __syncthreads();
  if (tid < KC) {
    float v = 0.f;
    #pragma unroll
    for (int q = 0; q < 8; ++q) v += redP[q][tid];
    ws[OFF_PP + (unsigned)b * KC + tid] = v;
  }
  if (tid < DD) {
    float v = 0.f;
    #pragma unroll
    for (int q = 0; q < 8; ++q) v += redS[q][tid];
    ws[OFF_SUMSP + (unsigned)b * DD + tid] = v;
  }
  if (tid == 0) ws[OFF_CNTP + b] = (float)m;
}

// Kernel B: ONE block, 1024 threads (16 waves). Wave w, lane j; rows
// i = w + 16q, q=0..3. Plain-stores out[0] — no atomic, no memset.
__global__ __launch_bounds__(1024) void k_final(const float* __restrict__ ws,
                                                float* __restrict__ out) {
  __shared__ __align__(16) float mu_t[DD][65];     // mu_t[d][r]
  __shared__ __align__(16) float means_s[KC][132]; // means_s[i][d], broadcast rows
  __shared__ float P_s[KC][65];                    // P totals
  __shared__ float cnt_s[KC];
  __shared__ float kap_sh[KC], logC_sh[KC], Aa_sh[KC];
  __shared__ float red[16];

  const int tid = threadIdx.x;
  const int w = tid >> 6, j = tid & 63;

  // stage mu (transposed): 2 float4 per thread
  const float4* mu4 = (const float4*)(ws + OFF_MUHAT);
  #pragma unroll
  for (int q = 0; q < 2; ++q) {
    int idx4 = q * 1024 + tid;
    float4 v = mu4[idx4];
    int idx = idx4 * 4;
    int r = idx >> 7, d = idx & 127;
    mu_t[d][r] = v.x; mu_t[d + 1][r] = v.y; mu_t[d + 2][r] = v.z; mu_t[d + 3][r] = v.w;
  }
  if (tid < KC) {
    float cv = 0.f;
    #pragma unroll
    for (int s = 0; s < 4; ++s) cv += ws[OFF_CNTP + s * 64 + tid];
    cnt_s[tid] = cv;
    kap_sh[tid]  = ws[OFF_KAP + tid];
    logC_sh[tid] = ws[OFF_LOGC + tid];
    Aa_sh[tid]   = ws[OFF_AA + tid];
  }
  // P totals: 4 elems per thread
  #pragma unroll
  for (int q = 0; q < 4; ++q) {
    int idx = q * 1024 + tid;          // idx = i*64 + jj
    int i = idx >> 6, jj = idx & 63;
    float v = 0.f;
    #pragma unroll
    for (int s = 0; s < 4; ++s) v += ws[OFF_PP + (unsigned)(s * 64 + i) * KC + jj];
    P_s[i][jj] = v;
  }
  __syncthreads();   // cnt_s ready before means fallback

  // means: 8 elems per thread
  #pragma unroll
  for (int q = 0; q < 8; ++q) {
    int idx = q * 1024 + tid;          // idx = i*128 + d
    int i = idx >> 7, d = idx & 127;
    float v = 0.f;
    #pragma unroll
    for (int s = 0; s < 4; ++s) v += ws[OFF_SUMSP + (unsigned)(s * 64 + i) * DD + d];
    float c = cnt_s[i];
    means_s[i][d] = (c == 0.f) ? mu_t[d][i] : v / fmaxf(c, 1.f);
  }
  __syncthreads();

  float kap_j = kap_sh[j], logC_j = logC_sh[j], Aa_j = Aa_sh[j];
  float cnt_j = cnt_s[j];
  float cs_j  = fmaxf(cnt_j, 1.f);

  float racc = 0.f, jacc = 0.f;
  #pragma unroll
  for (int q = 0; q < 4; ++q) {
    int i = w + 16 * q;
    float kap_i = kap_sh[i], logC_i = logC_sh[i], Aa_i = Aa_sh[i];
    float cnt_i = cnt_s[i];
    float cs_i  = fmaxf(cnt_i, 1.f);

    float e0 = 0.f, e1 = 0.f;
    #pragma unroll
    for (int d = 0; d < DD; d += 4) {
      float4 mb = *(const float4*)&means_s[i][d];   // broadcast
      e0 += mb.x * mu_t[d][j]     + mb.z * mu_t[d + 2][j];
      e1 += mb.y * mu_t[d + 1][j] + mb.w * mu_t[d + 3][j];
    }
    float dot_j = e0 + e1;
    float diag  = __shfl(dot_j, i, 64);
    float wgt   = fabsf((float)(i - j));
    float diff  = kap_i * diag - kap_j * dot_j;
    float hinge = (i == j) ? 0.f : fmaxf(0.f, 0.5f * wgt - diff);
    racc += wave_sum(hinge) / cs_i;

    float js_v;
    if (cnt_i == 0.f || cnt_j == 0.f) {
      float md = 0.f;
      for (int d = 0; d < DD; ++d) md += mu_t[d][i] * mu_t[d][j];
      float kl_ij = logC_i - logC_j + Aa_i * (kap_i - kap_j * md);
      float kl_ji = logC_j - logC_i + Aa_j * (kap_j - kap_i * md);
      js_v = 0.5f * (kl_ij + kl_ji);
    } else {
      js_v = 0.5f * (P_s[i][j] / cs_i + P_s[j][i] / cs_j);
    }
    jacc += wave_sum(wgt * js_v);
  }

  if (j == 0) red[w] = racc * (1.f / 4096.f) + jacc * (1.f / 87360.f);
  __syncthreads();
  if (tid == 0) {
    float t = 0.f;
    #pragma unroll
    for (int q = 0; q < 16; ++q) t += red[q];
    out[0] = t;
  }
}

extern "C" void kernel_launch(void* const* d_in, const int* in_sizes, int n_in,
                              void* d_out, int out_size, void* d_ws, size_t ws_size,
                              hipStream_t stream) {
  const float* feat = (const float*)d_in[0];
  const float* musp = (const float*)d_in[1];
  const float* rho  = (const float*)d_in[2];
  const int*   lab  = (const int*)d_in[3];
  float* ws  = (float*)d_ws;
  float* out = (float*)d_out;

  k_classes<<<256, 512, 0, stream>>>(feat, musp, rho, lab, ws);
  k_final<<<1, 1024, 0, stream>>>(ws, out);
}

// Round 6
// 75.458 us; speedup vs baseline: 1.1886x; 1.1886x over previous
//
#include <hip/hip_runtime.h>
#include <hip/hip_bf16.h>
#include <math.h>

#define KC 64
#define DD 128
#define NN 4096

// ws float offsets
#define OFF_MUHAT 0u       // 8192
#define OFF_KAP   8192u    // 64
#define OFF_LOGC  8256u    // 64
#define OFF_AA    8320u    // 64
#define OFF_SUMSP 8384u    // 256*128 = 32768  (per-block class-sum partials)
#define OFF_CNTP  41152u   // 256               (per-block count partials)
#define OFF_PP    41408u   // 256*64 = 16384    (per-block P-row partials)

#define LOG2PI 1.8378770664093453f
#define LN2    0.6931471805599453f
#define GAMMALN64 201.00931639928152f

__device__ __forceinline__ float wave_sum(float v) {
  #pragma unroll
  for (int off = 32; off > 0; off >>= 1) v += __shfl_xor(v, off, 64);
  return v;
}

// Kernel A: block b = (sub, c); sub = b>>6 owns rows [sub*1024, +1024),
// c = b&63 owns class c. Normalizes its rows in-reg, computes L[n,:] via
// LDS dot, accumulates P-row-c / class-sum / count with NO global atomics.
__global__ __launch_bounds__(512) void k_classes(const float* __restrict__ feat,
                                                 const float* __restrict__ musp,
                                                 const float* __restrict__ rho,
                                                 const int* __restrict__ lab,
                                                 float* __restrict__ ws,
                                                 float* __restrict__ out) {
  __shared__ __align__(16) float mu_t[DD][65];   // mu_t[d][r] = muhat[r][d]
  __shared__ float kap_s[KC], logC_s[KC];
  __shared__ __align__(16) float f_s[8][132];
  __shared__ float redS[8][DD];
  __shared__ float redP[8][KC];
  __shared__ int wl[1024];
  __shared__ int wl_cnt;

  const int tid = threadIdx.x;
  const int w = tid >> 6, l = tid & 63;
  const int b = blockIdx.x, c = b & 63, sub = b >> 6;
  if (tid == 0) wl_cnt = 0;
  if (b == 0 && tid == 0) out[0] = 0.f;   // zero accumulator for k_final

  // stage normalized mus (transposed) — redundant per block, trivial
  #pragma unroll
  for (int rr = 0; rr < 8; ++rr) {
    int r = w * 8 + rr;
    float x0 = musp[r * DD + l];
    float x1 = musp[r * DD + 64 + l];
    float ss = wave_sum(x0 * x0 + x1 * x1);
    float inv = 1.f / fmaxf(sqrtf(ss), 1e-12f);
    mu_t[l][r]      = x0 * inv;
    mu_t[l + 64][r] = x1 * inv;
  }
  if (tid < KC) {
    float x = rho[tid];
    float sp = fmaxf(x, 0.f) + log1pf(expf(-fabsf(x)));
    float kp = fmaxf(sp, 1e-6f);
    kap_s[tid] = kp;
    float logI;
    if (kp < 1e-3f)
      logI = 63.f * logf(kp * 0.5f + 1e-12f) - GAMMALN64;
    else
      logI = kp - 0.5f * logf(6.283185307179586f * kp + 1e-12f);
    logC_s[tid] = -63.f * logf(kp + 1e-12f) - 64.f * LOG2PI - logI;
  }
  __syncthreads();

  // block 0 publishes muhat + per-class consts for k_final
  if (b == 0) {
    for (int idx = tid; idx < KC * DD; idx += 512)
      ws[OFF_MUHAT + idx] = mu_t[idx & 127][idx >> 7];
    if (tid < KC) {
      float kp = kap_s[tid];
      float kc = fmaxf(kp, 1e-8f);
      float Aav = (kc > 50.f) ? (1.f - 127.f / (2.f * kc)) : (kc * (1.f / 128.f));
      ws[OFF_KAP + tid]  = kp;
      ws[OFF_LOGC + tid] = logC_s[tid];
      ws[OFF_AA + tid]   = Aav;
    }
  }

  // worklist: rows in our window with label == c
  const int base = sub * 1024;
  for (int t = tid; t < 1024; t += 512) {
    if (lab[base + t] == c) {
      int p = atomicAdd(&wl_cnt, 1);   // LDS atomic, tiny
      wl[p] = base + t;
    }
  }
  __syncthreads();
  const int m = wl_cnt;

  float accP = 0.f, s0 = 0.f, s1 = 0.f;
  const float2* feat2 = (const float2*)feat;
  for (int e = w; e < m; e += 8) {
    int n = wl[e];
    float2 f2 = feat2[n * 64 + l];                 // lane l holds dims 2l, 2l+1
    float ss = wave_sum(f2.x * f2.x + f2.y * f2.y);
    float inv = 1.f / fmaxf(sqrtf(ss), 1e-12f);
    float x0 = f2.x * inv, x1 = f2.y * inv;
    s0 += x0; s1 += x1;
    *(float2*)&f_s[w][2 * l] = make_float2(x0, x1); // per-wave buffer
    __builtin_amdgcn_wave_barrier();                // pin order: write before reads
    float acc0 = 0.f, acc1 = 0.f;
    #pragma unroll
    for (int d = 0; d < DD; d += 4) {
      float4 fb = *(const float4*)&f_s[w][d];       // broadcast read
      acc0 += fb.x * mu_t[d][l]     + fb.z * mu_t[d + 2][l];
      acc1 += fb.y * mu_t[d + 1][l] + fb.w * mu_t[d + 3][l];
    }
    float Lj = logC_s[l] + kap_s[l] * (acc0 + acc1);
    float a = __shfl(Lj, c, 64);                    // L[n, c]
    float mm = fmaxf(a, Lj);
    accP += a + LN2 - (mm + log1pf(expf(-fabsf(a - Lj))));
  }

  // cross-wave reduce, plain stores (no global atomics)
  redP[w][l] = accP;
  redS[w][2 * l] = s0;
  redS[w][2 * l + 1] = s1;
  __syncthreads();
  if (tid < KC) {
    float v = 0.f;
    #pragma unroll
    for (int q = 0; q < 8; ++q) v += redP[q][tid];
    ws[OFF_PP + (unsigned)b * KC + tid] = v;
  }
  if (tid < DD) {
    float v = 0.f;
    #pragma unroll
    for (int q = 0; q < 8; ++q) v += redS[q][tid];
    ws[OFF_SUMSP + (unsigned)b * DD + tid] = v;
  }
  if (tid == 0) ws[OFF_CNTP + b] = (float)m;
}

// element d (compile-time) of a float4[32] register row
#define MUROW(d) ((d & 3) == 0 ? murow[(d) >> 2].x : (d & 3) == 1 ? murow[(d) >> 2].y : \
                  (d & 3) == 2 ? murow[(d) >> 2].z : murow[(d) >> 2].w)

// Kernel B: 64 blocks x 1 wave. Block i, lane j handles pair (i,j).
// No LDS; mu-row-j in regs; broadcasts via shfl; ~55 independent loads/lane.
__global__ __launch_bounds__(64) void k_final(const float* __restrict__ ws,
                                              float* __restrict__ out) {
  const int j = threadIdx.x, i = blockIdx.x;

  // mu-hat row j in registers (32 float4, fully static indexing)
  const float4* mu4 = (const float4*)(ws + OFF_MUHAT);
  float4 murow[32];
  #pragma unroll
  for (int q = 0; q < 32; ++q) murow[q] = mu4[j * 32 + q];

  float cnt_j = 0.f;
  #pragma unroll
  for (int s = 0; s < 4; ++s) cnt_j += ws[OFF_CNTP + s * 64 + j];
  float cs_j  = fmaxf(cnt_j, 1.f);
  float cnt_i = __shfl(cnt_j, i, 64);
  float cs_i  = fmaxf(cnt_i, 1.f);

  float kap_j  = ws[OFF_KAP + j],  kap_i  = __shfl(kap_j, i, 64);
  float logC_j = ws[OFF_LOGC + j], logC_i = __shfl(logC_j, i, 64);
  float Aa_j   = ws[OFF_AA + j],   Aa_i   = __shfl(Aa_j, i, 64);

  // means row i, distributed: lane j holds dims j and j+64
  float m0 = 0.f, m1 = 0.f;
  #pragma unroll
  for (int s = 0; s < 4; ++s) {
    m0 += ws[OFF_SUMSP + (unsigned)(s * 64 + i) * DD + j];
    m1 += ws[OFF_SUMSP + (unsigned)(s * 64 + i) * DD + 64 + j];
  }
  if (cnt_i == 0.f) {                       // wave-uniform, never in practice
    m0 = ws[OFF_MUHAT + (unsigned)i * DD + j];
    m1 = ws[OFF_MUHAT + (unsigned)i * DD + 64 + j];
  } else {
    m0 /= cs_i; m1 /= cs_i;
  }

  // dot_j = <means_i, mu_j> via shfl-broadcast, fully unrolled
  float dot = 0.f;
  #pragma unroll
  for (int d = 0; d < 64; ++d) dot += __shfl(m0, d, 64) * MUROW(d);
  #pragma unroll
  for (int d = 0; d < 64; ++d) dot += __shfl(m1, d, 64) * MUROW(d + 64);

  float diag  = __shfl(dot, i, 64);
  float wgt   = fabsf((float)(i - j));
  float diff  = kap_i * diag - kap_j * dot;
  float hinge = (i == j) ? 0.f : fmaxf(0.f, 0.5f * wgt - diff);
  float rank_part = wave_sum(hinge) / cs_i;

  float Pij = 0.f, Pji = 0.f;
  #pragma unroll
  for (int s = 0; s < 4; ++s) {
    Pij += ws[OFF_PP + (unsigned)(s * 64 + i) * KC + j];
    Pji += ws[OFF_PP + (unsigned)(s * 64 + j) * KC + i];
  }
  float js_v = 0.5f * (Pij / cs_i + Pji / cs_j);

  // zero-count fallback (exact, statistically never taken; wave-uniform guard)
  if (cnt_i == 0.f || __ballot(cnt_j == 0.f)) {
    float mi0 = ws[OFF_MUHAT + (unsigned)i * DD + j];
    float mi1 = ws[OFF_MUHAT + (unsigned)i * DD + 64 + j];
    float md = 0.f;
    #pragma unroll
    for (int d = 0; d < 64; ++d) md += __shfl(mi0, d, 64) * MUROW(d);
    #pragma unroll
    for (int d = 0; d < 64; ++d) md += __shfl(mi1, d, 64) * MUROW(d + 64);
    float kl_ij = logC_i - logC_j + Aa_i * (kap_i - kap_j * md);
    float kl_ji = logC_j - logC_i + Aa_j * (kap_j - kap_i * md);
    if (cnt_i == 0.f || cnt_j == 0.f) js_v = 0.5f * (kl_ij + kl_ji);
  }
  float js_part = wave_sum(wgt * js_v);
  if (j == 0)
    atomicAdd(out, rank_part * (1.f / 4096.f) + js_part * (1.f / 87360.f));
}

extern "C" void kernel_launch(void* const* d_in, const int* in_sizes, int n_in,
                              void* d_out, int out_size, void* d_ws, size_t ws_size,
                              hipStream_t stream) {
  const float* feat = (const float*)d_in[0];
  const float* musp = (const float*)d_in[1];
  const float* rho  = (const float*)d_in[2];
  const int*   lab  = (const int*)d_in[3];
  float* ws  = (float*)d_ws;
  float* out = (float*)d_out;

  k_classes<<<256, 512, 0, stream>>>(feat, musp, rho, lab, ws, out);
  k_final<<<64, 64, 0, stream>>>(ws, out);
}